// Round 1
// baseline (826.606 us; speedup 1.0000x reference)
//
#include <hip/hip_runtime.h>

#define GRID_W 64
#define NPTS   4096      // 64*64
#define BATCH  8
#define DD     32        // D
#define DANC   16
#define DIN    80        // 2*D + D_ANCIL
#define HID    128
#define W1T_STRIDE 84    // 80 padded to keep 16B alignment & break bank stride

// One half-step: state[dstoff] += dt * F(state[srcoff], xi)
// Block = 128 threads, handles 64 points; each point is split across two
// lanes (j-halves 0..63 / 64..127), combined with shfl_xor(32).
__global__ __launch_bounds__(128, 1) void f_eval(
    float* __restrict__ state,
    const float* __restrict__ W1, const float* __restrict__ b1,
    const float* __restrict__ W2, const float* __restrict__ b2,
    const float* __restrict__ tfinal,
    int srcoff, int dstoff, float tcur, float dtmax)
{
    __shared__ float sW1t[HID * W1T_STRIDE];
    __shared__ float sW2[HID * DD];
    __shared__ float sB1[HID];

    const int tid    = threadIdx.x;
    const int ptBase = blockIdx.x * 64;          // 512 blocks * 64 pts
    const int b      = ptBase >> 12;             // batch (block-uniform)

    const float tf = tfinal[b];
    float dt = fminf(fmaxf(tf - tcur, 0.0f), dtmax);
    if (dt <= 0.0f) return;                      // exact: q + 0*F == q

    // ---- stage weights into LDS ----
    const float4* W1v = (const float4*)W1;       // W1 is [k(80)][j(128)] row-major
    for (int idx = tid; idx < (DIN * HID) / 4; idx += 128) {
        int kk = idx >> 5;                       // k = 0..79
        int j4 = (idx & 31) << 2;                // j base
        float4 v = W1v[idx];
        sW1t[(j4 + 0) * W1T_STRIDE + kk] = v.x;
        sW1t[(j4 + 1) * W1T_STRIDE + kk] = v.y;
        sW1t[(j4 + 2) * W1T_STRIDE + kk] = v.z;
        sW1t[(j4 + 3) * W1T_STRIDE + kk] = v.w;
    }
    const float4* W2v = (const float4*)W2;
    float4* sW2v = (float4*)sW2;
    for (int idx = tid; idx < (HID * DD) / 4; idx += 128) sW2v[idx] = W2v[idx];
    if (tid < HID) sB1[tid] = b1[tid];
    __syncthreads();

    // ---- thread -> (point, j-half) mapping ----
    const int wave    = tid >> 6;
    const int lane    = tid & 63;
    const int ptLocal = wave * 32 + (lane & 31);
    const int jBase   = (lane >> 5) << 6;        // 0 or 64
    const int g       = ptBase + ptLocal;        // global point index
    const int i       = g & (NPTS - 1);          // index within batch
    const int r = i >> 6, c = i & 63;
    const int rm = (r + 63) & 63, rp = (r + 1) & 63;
    const int cm = (c + 63) & 63, cp = (c + 1) & 63;

    const float* bbase = state + (size_t)(g - i) * DIN;   // batch base

    // ---- gather u = [z_self, mean(z_nbr), xi] ----
    float u[DIN];
    {
        const float* ps = bbase + (size_t)i * DIN + srcoff;
        #pragma unroll
        for (int d = 0; d < DD; d += 4) {
            float4 v = *(const float4*)(ps + d);
            u[d] = v.x; u[d+1] = v.y; u[d+2] = v.z; u[d+3] = v.w;
        }
    }
    #pragma unroll
    for (int d = 0; d < DD; ++d) u[DD + d] = 0.0f;
    const int nb[4] = { rm*GRID_W + c, rp*GRID_W + c, r*GRID_W + cm, r*GRID_W + cp };
    #pragma unroll
    for (int t = 0; t < 4; ++t) {
        const float* pn = bbase + (size_t)nb[t] * DIN + srcoff;
        #pragma unroll
        for (int d = 0; d < DD; d += 4) {
            float4 v = *(const float4*)(pn + d);
            u[DD+d] += v.x; u[DD+d+1] += v.y; u[DD+d+2] += v.z; u[DD+d+3] += v.w;
        }
    }
    #pragma unroll
    for (int d = 0; d < DD; ++d) u[DD + d] *= 0.25f;
    {
        const float* px = bbase + (size_t)i * DIN + 2 * DD;
        #pragma unroll
        for (int d = 0; d < DANC; d += 4) {
            float4 v = *(const float4*)(px + d);
            u[64+d] = v.x; u[64+d+1] = v.y; u[64+d+2] = v.z; u[64+d+3] = v.w;
        }
    }

    // ---- MLP over this thread's 64 hidden units ----
    float acc[DD];
    #pragma unroll
    for (int d = 0; d < DD; ++d) acc[d] = 0.0f;

    for (int jj = 0; jj < 64; ++jj) {
        const int j = jBase + jj;
        float s = sB1[j];
        const float* wrow = &sW1t[j * W1T_STRIDE];
        #pragma unroll
        for (int k = 0; k < DIN; k += 4) {
            float4 w = *(const float4*)(wrow + k);
            s += u[k]   * w.x; s += u[k+1] * w.y;
            s += u[k+2] * w.z; s += u[k+3] * w.w;
        }
        // tanh(s) = 1 - 2/(exp(2s)+1)  (stable at +/-inf)
        float e = __expf(2.0f * s);
        float h = 1.0f - __fdividef(2.0f, e + 1.0f);
        const float* w2row = &sW2[j * DD];
        #pragma unroll
        for (int d = 0; d < DD; d += 4) {
            float4 w = *(const float4*)(w2row + d);
            acc[d]   += h * w.x; acc[d+1] += h * w.y;
            acc[d+2] += h * w.z; acc[d+3] += h * w.w;
        }
    }

    // combine the two j-halves of each point
    #pragma unroll
    for (int d = 0; d < DD; ++d) acc[d] += __shfl_xor(acc[d], 32, 64);

    // ---- update dst in place (halves write disjoint d-ranges) ----
    float* pd = state + (size_t)g * DIN + dstoff;
    if (lane < 32) {
        #pragma unroll
        for (int d = 0; d < 16; d += 4) {
            float4 o = *(const float4*)(pd + d);
            o.x += dt * (acc[d]   + b2[d]);
            o.y += dt * (acc[d+1] + b2[d+1]);
            o.z += dt * (acc[d+2] + b2[d+2]);
            o.w += dt * (acc[d+3] + b2[d+3]);
            *(float4*)(pd + d) = o;
        }
    } else {
        #pragma unroll
        for (int d = 16; d < 32; d += 4) {
            float4 o = *(const float4*)(pd + d);
            o.x += dt * (acc[d]   + b2[d]);
            o.y += dt * (acc[d+1] + b2[d+1]);
            o.z += dt * (acc[d+2] + b2[d+2]);
            o.w += dt * (acc[d+3] + b2[d+3]);
            *(float4*)(pd + d) = o;
        }
    }
}

extern "C" void kernel_launch(void* const* d_in, const int* in_sizes, int n_in,
                              void* d_out, int out_size, void* d_ws, size_t ws_size,
                              hipStream_t stream)
{
    const float* x   = (const float*)d_in[0];
    const float* tf  = (const float*)d_in[1];
    const float* W1q = (const float*)d_in[2];
    const float* b1q = (const float*)d_in[3];
    const float* W2q = (const float*)d_in[4];
    const float* b2q = (const float*)d_in[5];
    const float* W1p = (const float*)d_in[6];
    const float* b1p = (const float*)d_in[7];
    const float* W2p = (const float*)d_in[8];
    const float* b2p = (const float*)d_in[9];
    float* out = (float*)d_out;

    // state lives in d_out: [b][i][q(32) p(32) xi(16)]
    hipMemcpyAsync(out, x, (size_t)BATCH * NPTS * DIN * sizeof(float),
                   hipMemcpyDeviceToDevice, stream);

    dim3 grid(512), block(128);
    const float DTc = 0.25f;
    float tq = 0.0f, tp = 0.0f;
    for (int k = 0; k < 18; ++k) {
        const float rho = (k == 0) ? 0.5f : 1.0f;
        // q += dt_q * F(p, xi; Wq)
        f_eval<<<grid, block, 0, stream>>>(out, W1q, b1q, W2q, b2q, tf,
                                           DD, 0, tq, rho * DTc);
        tq += rho * DTc;
        // p += dt_p * F(q, xi; Wp)
        f_eval<<<grid, block, 0, stream>>>(out, W1p, b1p, W2p, b2p, tf,
                                           0, DD, tp, DTc);
        tp += DTc;
    }
}

// Round 2
// 416.563 us; speedup vs baseline: 1.9843x; 1.9843x over previous
//
#include <hip/hip_runtime.h>
#include <hip/hip_bf16.h>

#define GRID_W 64
#define NPTS   4096
#define BATCH  8
#define DD     32
#define DIN    80
#define KP     96          // K padded to 3*32 for mfma 16x16x32
#define HID    128
#define TM     64          // points per block
#define SA_STRIDE 104      // ushort stride: 208B = 13*16B aligned, 2-way banks
#define SH_STRIDE 136      // ushort stride: 272B = 17*16B aligned, 2-way banks

typedef __attribute__((ext_vector_type(8))) short short8;
typedef __attribute__((ext_vector_type(4))) float f32x4;

__device__ __forceinline__ ushort f2bf(float v) {
    __hip_bfloat16 h = __float2bfloat16(v);
    return __builtin_bit_cast(ushort, h);
}
__device__ __forceinline__ uint packbf(float a, float b) {
    return (uint)f2bf(a) | ((uint)f2bf(b) << 16);
}

// One half-step: state[dstoff] += dt * F(state[srcoff], xi), via bf16 MFMA.
__global__ __launch_bounds__(256, 2) void f_eval(
    float* __restrict__ state,
    const float* __restrict__ W1, const float* __restrict__ b1,
    const float* __restrict__ W2, const float* __restrict__ b2,
    const float* __restrict__ tfinal,
    int srcoff, int dstoff, float tcur, float dtmax)
{
    __shared__ __align__(16) char sAO_raw[TM * SA_STRIDE * 2];  // sA(bf16) / sO(f32) overlay
    __shared__ ushort sW1T[HID * SA_STRIDE];  // [n=128][k=96 pad 104]
    __shared__ ushort sH[TM * SH_STRIDE];     // [m=64][k=128 pad 136]
    __shared__ ushort sW2T[DD * SH_STRIDE];   // [n=32][k=128 pad 136]
    __shared__ float  sB1[HID];

    ushort* sA = (ushort*)sAO_raw;
    float*  sO = (float*)sAO_raw;

    const int tid  = threadIdx.x;
    const int tile = blockIdx.x & 63;          // grid row handled by this block
    const int b    = blockIdx.x >> 6;          // batch

    const float tf = tfinal[b];
    float dt = fminf(fmaxf(tf - tcur, 0.0f), dtmax);
    if (dt <= 0.0f) return;                    // exact: z + 0*F == z

    // ---------- phase 0: stage weights (bf16, transposed) ----------
    for (int idx = tid; idx < HID * KP; idx += 256) {      // 12288
        int k = idx >> 7, n = idx & 127;                   // coalesced read
        float v = (k < DIN) ? W1[k * HID + n] : 0.0f;
        sW1T[n * SA_STRIDE + k] = f2bf(v);
    }
    for (int idx = tid; idx < HID * DD; idx += 256) {      // 4096
        int k = idx >> 5, n = idx & 31;
        sW2T[n * SH_STRIDE + k] = f2bf(W2[k * DD + n]);
    }
    if (tid < HID) sB1[tid] = b1[tid];

    // ---------- phase 0b: gather u -> sA (4 threads per point) ----------
    {
        const int t    = tid & 63;             // point = column c
        const int part = tid >> 6;
        const int r  = tile, c = t;
        const int rm = (r + 63) & 63, rp = (r + 1) & 63;
        const int cm = (c + 63) & 63, cp = (c + 1) & 63;
        const float* bb = state + (size_t)b * NPTS * DIN;
        const float* self = bb + (size_t)(r * GRID_W + c) * DIN;
        ushort* row = &sA[t * SA_STRIDE];

        if (part == 0) {                       // u[0:32] = z_self
            #pragma unroll
            for (int d = 0; d < 32; d += 4) {
                float4 v = *(const float4*)(self + srcoff + d);
                *(uint*)&row[d]     = packbf(v.x, v.y);
                *(uint*)&row[d + 2] = packbf(v.z, v.w);
            }
        } else if (part == 1) {                // u[64:80] = xi, u[80:96] = 0
            #pragma unroll
            for (int d = 0; d < 16; d += 4) {
                float4 v = *(const float4*)(self + 2 * DD + d);
                *(uint*)&row[64 + d]     = packbf(v.x, v.y);
                *(uint*)&row[64 + d + 2] = packbf(v.z, v.w);
            }
            #pragma unroll
            for (int d = 0; d < 16; d += 2) *(uint*)&row[80 + d] = 0u;
        } else {                               // u[32+off : 48+off] = nbr mean
            const int off = (part == 2) ? 0 : 16;
            const float* n0 = bb + (size_t)(rm * GRID_W + c) * DIN + srcoff + off;
            const float* n1 = bb + (size_t)(rp * GRID_W + c) * DIN + srcoff + off;
            const float* n2 = bb + (size_t)(r * GRID_W + cm) * DIN + srcoff + off;
            const float* n3 = bb + (size_t)(r * GRID_W + cp) * DIN + srcoff + off;
            #pragma unroll
            for (int d = 0; d < 16; d += 4) {
                float4 a0 = *(const float4*)(n0 + d);
                float4 a1 = *(const float4*)(n1 + d);
                float4 a2 = *(const float4*)(n2 + d);
                float4 a3 = *(const float4*)(n3 + d);
                float x0 = 0.25f * (a0.x + a1.x + a2.x + a3.x);
                float x1 = 0.25f * (a0.y + a1.y + a2.y + a3.y);
                float x2 = 0.25f * (a0.z + a1.z + a2.z + a3.z);
                float x3 = 0.25f * (a0.w + a1.w + a2.w + a3.w);
                *(uint*)&row[32 + off + d]     = packbf(x0, x1);
                *(uint*)&row[32 + off + d + 2] = packbf(x2, x3);
            }
        }
    }
    __syncthreads();

    // ---------- phase 1: H = tanh(A @ W1 + b1), per-wave 16 rows ----------
    const int wv   = tid >> 6;                 // 0..3 -> m-tile
    const int lane = tid & 63;
    const int l16  = lane & 15;
    const int quad = lane >> 4;

    f32x4 acc1[8];
    #pragma unroll
    for (int nt = 0; nt < 8; ++nt) acc1[nt] = (f32x4){0.f, 0.f, 0.f, 0.f};

    const int arow = wv * 16 + l16;
    #pragma unroll
    for (int ks = 0; ks < 3; ++ks) {
        short8 af = *(const short8*)&sA[arow * SA_STRIDE + ks * 32 + quad * 8];
        #pragma unroll
        for (int nt = 0; nt < 8; ++nt) {
            short8 bf = *(const short8*)&sW1T[(nt * 16 + l16) * SA_STRIDE + ks * 32 + quad * 8];
            acc1[nt] = __builtin_amdgcn_mfma_f32_16x16x32_bf16(af, bf, acc1[nt], 0, 0, 0);
        }
    }

    // tanh + write H (bf16) to LDS; C-layout: col=lane&15, row=quad*4+reg
    #pragma unroll
    for (int nt = 0; nt < 8; ++nt) {
        const int col = nt * 16 + l16;
        const float bias = sB1[col];
        #pragma unroll
        for (int rg = 0; rg < 4; ++rg) {
            const int rowm = wv * 16 + quad * 4 + rg;
            float s = acc1[nt][rg] + bias;
            float e = __expf(2.0f * s);
            float h = 1.0f - __fdividef(2.0f, e + 1.0f);
            sH[rowm * SH_STRIDE + col] = f2bf(h);
        }
    }
    __syncthreads();   // also guards sO-over-sA reuse below

    // ---------- phase 2: O = H @ W2 + b2 ----------
    f32x4 acc2[2];
    acc2[0] = (f32x4){0.f, 0.f, 0.f, 0.f};
    acc2[1] = (f32x4){0.f, 0.f, 0.f, 0.f};
    #pragma unroll
    for (int ks = 0; ks < 4; ++ks) {
        short8 af = *(const short8*)&sH[arow * SH_STRIDE + ks * 32 + quad * 8];
        #pragma unroll
        for (int nt = 0; nt < 2; ++nt) {
            short8 bf = *(const short8*)&sW2T[(nt * 16 + l16) * SH_STRIDE + ks * 32 + quad * 8];
            acc2[nt] = __builtin_amdgcn_mfma_f32_16x16x32_bf16(af, bf, acc2[nt], 0, 0, 0);
        }
    }
    #pragma unroll
    for (int nt = 0; nt < 2; ++nt) {
        const int col = nt * 16 + l16;
        const float b2v = b2[col];
        #pragma unroll
        for (int rg = 0; rg < 4; ++rg) {
            const int rowm = wv * 16 + quad * 4 + rg;
            sO[rowm * DD + col] = acc2[nt][rg] + b2v;
        }
    }
    __syncthreads();

    // ---------- epilogue: state[dst] += dt * O (vectorized RMW) ----------
    float* bb = state + (size_t)b * NPTS * DIN;
    #pragma unroll
    for (int it = 0; it < 2; ++it) {
        const int idx = tid + it * 256;        // 512 float4 slots
        const int pt  = idx >> 3;
        const int seg = (idx & 7) << 2;
        float* pd = bb + (size_t)(tile * TM + pt) * DIN + dstoff + seg;
        const float* po = &sO[pt * DD + seg];
        float4 o = *(const float4*)pd;
        o.x += dt * po[0]; o.y += dt * po[1];
        o.z += dt * po[2]; o.w += dt * po[3];
        *(float4*)pd = o;
    }
}

extern "C" void kernel_launch(void* const* d_in, const int* in_sizes, int n_in,
                              void* d_out, int out_size, void* d_ws, size_t ws_size,
                              hipStream_t stream)
{
    const float* x   = (const float*)d_in[0];
    const float* tf  = (const float*)d_in[1];
    const float* W1q = (const float*)d_in[2];
    const float* b1q = (const float*)d_in[3];
    const float* W2q = (const float*)d_in[4];
    const float* b2q = (const float*)d_in[5];
    const float* W1p = (const float*)d_in[6];
    const float* b1p = (const float*)d_in[7];
    const float* W2p = (const float*)d_in[8];
    const float* b2p = (const float*)d_in[9];
    float* out = (float*)d_out;

    hipMemcpyAsync(out, x, (size_t)BATCH * NPTS * DIN * sizeof(float),
                   hipMemcpyDeviceToDevice, stream);

    dim3 grid(512), block(256);
    const float DTc = 0.25f;
    float tq = 0.0f, tp = 0.0f;
    for (int k = 0; k < 18; ++k) {
        const float rho = (k == 0) ? 0.5f : 1.0f;
        f_eval<<<grid, block, 0, stream>>>(out, W1q, b1q, W2q, b2q, tf,
                                           DD, 0, tq, rho * DTc);
        tq += rho * DTc;
        f_eval<<<grid, block, 0, stream>>>(out, W1p, b1p, W2p, b2p, tf,
                                           0, DD, tp, DTc);
        tp += DTc;
    }
}